// Round 7
// baseline (531.486 us; speedup 1.0000x reference)
//
#include <hip/hip_runtime.h>
#include <hip/hip_bf16.h>
#include <math.h>

#define N_NODES 50000
#define NFEAT 256
#define NHID 64
#define HOPS 4
#define NEDGES 800000
#define NBINS (HOPS * N_NODES)      // 200000 per-(hop,row) bins

#define CHUNK 4096                   // edges per block in edge-parallel kernels
#define NCHUNK ((NEDGES + CHUNK - 1) / CHUNK)  // 196
#define MCAP 512                     // staged edges per gather wave (mean 256, 16 sigma)
#define NTILE ((NBINS + 1023) / 1024)          // 196 scan tiles of 1024 bins

// MFMA GEMM tile config
#define GM 64                        // rows per block
#define LDP 40                       // LDS k-stride in bf16 (80 B: 16B-aligned, 2-way banks)
#define NGBLK ((N_NODES + GM - 1) / GM)   // 782

// prep fusion block ranges
#define PREP_RHIST (NCHUNK * HOPS)                            // 784
#define PREP_CASTW_END (PREP_RHIST + 256)                     // 1040
#define PREP_CASTX_BLKS ((N_NODES * NFEAT / 8) / 256)         // 6250 (exact)
#define PREP_TOTAL (PREP_CASTW_END + PREP_CASTX_BLKS)         // 7290

typedef short bf16x8 __attribute__((ext_vector_type(8)));
typedef float f32x4 __attribute__((ext_vector_type(4)));

static __device__ __forceinline__ unsigned short f2bf(float f) {
    __hip_bfloat16 h = __float2bfloat16(f);
    return *reinterpret_cast<unsigned short*>(&h);
}

// ---------------------------------------------------------------------------
// K1: fused prep = rhist (blocks 0..783) || castw (784..1039) ||
//     castx (1040..7289).
// rhist: per-(hop,row) histogram via GLOBAL int atomics (native, L2-absorbed;
// 3.2M adds over 200K bins = ~16/address). Replaces the LDS bucket histogram
// -> no LDS, no barriers in this branch.
// ---------------------------------------------------------------------------
__global__ __launch_bounds__(256) void prep_kernel(const float* __restrict__ x,
                                                   unsigned short* __restrict__ Xbf,
                                                   const float* __restrict__ W,
                                                   unsigned short* __restrict__ Wt,
                                                   const int* __restrict__ rows,
                                                   int* __restrict__ cnt) {
    const int bid = blockIdx.x;
    const int t = threadIdx.x;

    if (bid < PREP_RHIST) {
        // ---- rhist: per-(hop,row) histogram, global atomics ----
        const int hop = bid / NCHUNK;
        const int e0 = (bid % NCHUNK) * CHUNK;
        const int n = min(CHUNK, NEDGES - e0);
        const size_t base = (size_t)hop * NEDGES + e0;
        const int binb = hop * N_NODES;
        for (int i = t; i < n; i += 256) {
            atomicAdd(&cnt[binb + rows[base + i]], 1);
        }
    } else if (bid < PREP_CASTW_END) {
        // ---- castw: W [hop][k][c] f32 -> Wt [k>>5][hop*64+c][k&31] bf16 ----
        const int idx = (bid - PREP_RHIST) * 256 + t;      // 65536 exact
        const int hop = idx >> 14;
        const int k = (idx >> 6) & 255;
        const int c = idx & 63;
        Wt[(size_t)(k >> 5) * (256 * 32) + (hop * 64 + c) * 32 + (k & 31)] = f2bf(W[idx]);
    } else {
        // ---- castx: x f32 -> Xbf bf16, 8 elems/thread (exact coverage) ----
        const size_t base = ((size_t)(bid - PREP_CASTW_END) * 256 + t) * 8;
        const float4 a = *(const float4*)&x[base];
        const float4 c = *(const float4*)&x[base + 4];
        unsigned short o[8] = {f2bf(a.x), f2bf(a.y), f2bf(a.z), f2bf(a.w),
                               f2bf(c.x), f2bf(c.y), f2bf(c.z), f2bf(c.w)};
        *(bf16x8*)&Xbf[base] = *(const bf16x8*)o;
    }
}

// ---------------------------------------------------------------------------
// K2: fused scanA (blocks 0..195) || gemm (blocks 196..977).
// scanA: tile j scans 1024 bins of cnt -> local exclusive prefixes into
// offsets[], tile total into tsum[j]. Tiny; hides entirely under the GEMM.
// ---------------------------------------------------------------------------
__global__ __launch_bounds__(256) void gemm_scan_kernel(const unsigned short* __restrict__ Xbf,
                                                        const unsigned short* __restrict__ Wt,
                                                        const float* __restrict__ b,
                                                        __hip_bfloat16* __restrict__ H,
                                                        const int* __restrict__ cnt,
                                                        int* __restrict__ offsets,
                                                        int* __restrict__ tsum) {
    __shared__ char smem[GM * LDP * 2 + 256 * LDP * 2];   // 25600 B
    const int t = threadIdx.x;

    if (blockIdx.x < NTILE) {
        // ---- scanA ----
        int* s = (int*)smem;
        const int j = blockIdx.x;
        const int i0 = j * 1024 + t * 4;
        int c[4];
        int tl = 0;
#pragma unroll
        for (int i = 0; i < 4; ++i) {
            const int idx = i0 + i;
            c[i] = (idx < NBINS) ? cnt[idx] : 0;
            tl += c[i];
        }
        s[t] = tl;
        __syncthreads();
        for (int off = 1; off < 256; off <<= 1) {
            const int a = (t >= off) ? s[t - off] : 0;
            __syncthreads();
            s[t] += a;
            __syncthreads();
        }
        int run = s[t] - tl;
#pragma unroll
        for (int i = 0; i < 4; ++i) {
            const int idx = i0 + i;
            if (idx <= NBINS) offsets[idx] = run;
            run += c[i];
        }
        if (t == 255) tsum[j] = run;               // tile total
        return;
    }

    // ---- gemm: H[n][c] = bf16( sum_k Xbf[n][k]*W[k][c] + b[c] ) ----
    unsigned short* A_lds = (unsigned short*)smem;                  // GM*LDP
    unsigned short* B_lds = (unsigned short*)(smem + GM * LDP * 2); // 256*LDP

    const int lane = t & 63;
    const int w = t >> 6;
    const int quad = lane >> 4;
    const int m16 = lane & 15;
    const int row0 = (blockIdx.x - NTILE) * GM;

    f32x4 acc[4][4];
#pragma unroll
    for (int mt = 0; mt < 4; ++mt)
#pragma unroll
        for (int nt = 0; nt < 4; ++nt) acc[mt][nt] = (f32x4){0.f, 0.f, 0.f, 0.f};

    for (int ks = 0; ks < 8; ++ks) {
        const int k0 = ks * 32;
        // A: thread t stages 8 bf16: row r = t>>2, k-octet (t&3)*8 (coalesced)
        {
            const int r = t >> 2;
            const int kq = (t & 3) * 8;
            bf16x8 v = {0, 0, 0, 0, 0, 0, 0, 0};
            if (row0 + r < N_NODES)
                v = *(const bf16x8*)&Xbf[(size_t)(row0 + r) * NFEAT + k0 + kq];
            *(bf16x8*)&A_lds[r * LDP + kq] = v;
        }
        // B: contiguous 16 KB ks-tile, 4 x 16 B per thread, fully coalesced
#pragma unroll
        for (int it = 0; it < 4; ++it) {
            const int i = t + it * 256;
            const bf16x8 v = *(const bf16x8*)&Wt[(size_t)ks * (256 * 32) + (size_t)i * 8];
            *(bf16x8*)&B_lds[(i >> 2) * LDP + (i & 3) * 8] = v;
        }
        __syncthreads();

        bf16x8 af[4], bf[4];
#pragma unroll
        for (int mt = 0; mt < 4; ++mt)
            af[mt] = *(const bf16x8*)&A_lds[(mt * 16 + m16) * LDP + quad * 8];
#pragma unroll
        for (int nt = 0; nt < 4; ++nt)
            bf[nt] = *(const bf16x8*)&B_lds[(w * 64 + nt * 16 + m16) * LDP + quad * 8];
#pragma unroll
        for (int mt = 0; mt < 4; ++mt)
#pragma unroll
            for (int nt = 0; nt < 4; ++nt)
                acc[mt][nt] = __builtin_amdgcn_mfma_f32_16x16x32_bf16(
                    af[mt], bf[nt], acc[mt][nt], 0, 0, 0);
        __syncthreads();
    }

#pragma unroll
    for (int nt = 0; nt < 4; ++nt) {
        const int col = w * 64 + nt * 16 + m16;
        const float bias = b[col];
#pragma unroll
        for (int mt = 0; mt < 4; ++mt) {
#pragma unroll
            for (int r = 0; r < 4; ++r) {
                const int row = row0 + mt * 16 + quad * 4 + r;
                if (row < N_NODES)
                    H[(size_t)row * 256 + col] = __float2bfloat16(acc[mt][nt][r] + bias);
            }
        }
    }
}

// ---------------------------------------------------------------------------
// K3: fixup - scan the 196 tile totals, add tile base to each local prefix
// in place; emit final offsets (CSR rowptr over 200K bins) + cursor copy.
// grid = NTILE blocks.
// ---------------------------------------------------------------------------
__global__ __launch_bounds__(256) void fixup_kernel(const int* __restrict__ tsum,
                                                    int* __restrict__ offsets,
                                                    int* __restrict__ cursor) {
    __shared__ int s[256];
    const int t = threadIdx.x;
    const int j = blockIdx.x;
    const int own = (t < NTILE) ? tsum[t] : 0;
    s[t] = own;
    __syncthreads();
    for (int off = 1; off < 256; off <<= 1) {
        const int a = (t >= off) ? s[t - off] : 0;
        __syncthreads();
        s[t] += a;
        __syncthreads();
    }
    const int base = (j > 0) ? s[j - 1] : 0;       // exclusive tile base
    const int i0 = j * 1024 + t * 4;
#pragma unroll
    for (int i = 0; i < 4; ++i) {
        const int idx = i0 + i;
        if (idx <= NBINS) {
            const int v = offsets[idx] + base;
            offsets[idx] = v;
            if (idx < NBINS) cursor[idx] = v;
        }
    }
}

// ---------------------------------------------------------------------------
// K4: place - one pass, no sort: pos = atomicAdd(cursor[bin]) gives the final
// slot; write {col, val} directly. Positions within a row are consecutive ->
// L2 sector-merged writes. 16 independent edges/thread -> full MLP, no
// barriers, no LDS. grid = (NCHUNK, HOPS)
// ---------------------------------------------------------------------------
__global__ __launch_bounds__(256) void place_kernel(const int* __restrict__ rows,
                                                    const int* __restrict__ cols,
                                                    const float* __restrict__ vals,
                                                    int* __restrict__ cursor,
                                                    int2* __restrict__ partbuf) {
    const int t = threadIdx.x;
    const int hop = blockIdx.y;
    const int e0 = blockIdx.x * CHUNK;
    const int n = min(CHUNK, NEDGES - e0);
    const size_t base = (size_t)hop * NEDGES + e0;
    const int binb = hop * N_NODES;
#pragma unroll
    for (int k = 0; k < CHUNK / 256; ++k) {
        const int i = t + k * 256;
        if (i < n) {
            const int r = rows[base + i];
            const int pos = atomicAdd(&cursor[binb + r], 1);
            partbuf[pos] = make_int2(cols[base + i], __float_as_int(vals[base + i]));
        }
    }
}

// ---------------------------------------------------------------------------
// Legacy f32-input GEMM (fallback path only).
// ---------------------------------------------------------------------------
__global__ __launch_bounds__(256) void gemm_mfma_kernel(const float* __restrict__ x,
                                                        const float* __restrict__ W,
                                                        const float* __restrict__ b,
                                                        __hip_bfloat16* __restrict__ H) {
    __shared__ unsigned short A_lds[GM * LDP];
    __shared__ unsigned short B_lds[256 * LDP];

    const int t = threadIdx.x;
    const int lane = t & 63;
    const int w = t >> 6;
    const int quad = lane >> 4;
    const int m16 = lane & 15;
    const int row0 = blockIdx.x * GM;

    f32x4 acc[4][4];
#pragma unroll
    for (int mt = 0; mt < 4; ++mt)
#pragma unroll
        for (int nt = 0; nt < 4; ++nt) acc[mt][nt] = (f32x4){0.f, 0.f, 0.f, 0.f};

    for (int ks = 0; ks < 8; ++ks) {
        const int k0 = ks * 32;
#pragma unroll
        for (int it = 0; it < 2; ++it) {
            const int i = t + it * 256;
            const int r = i >> 3;
            const int kq = (i & 7) * 4;
            float4 v = make_float4(0.f, 0.f, 0.f, 0.f);
            if (row0 + r < N_NODES)
                v = *(const float4*)&x[(size_t)(row0 + r) * NFEAT + k0 + kq];
            unsigned short* d = &A_lds[r * LDP + kq];
            d[0] = f2bf(v.x); d[1] = f2bf(v.y); d[2] = f2bf(v.z); d[3] = f2bf(v.w);
        }
#pragma unroll
        for (int it = 0; it < 8; ++it) {
            const int i = t + it * 256;
            const int n4 = i & 63;
            const int kk = i >> 6;
            const int hop = n4 >> 4;
            const int j = (n4 & 15) * 4;
            const float4 v = *(const float4*)&W[(size_t)hop * (NFEAT * NHID)
                                                + (size_t)(k0 + kk) * NHID + j];
            B_lds[(n4 * 4 + 0) * LDP + kk] = f2bf(v.x);
            B_lds[(n4 * 4 + 1) * LDP + kk] = f2bf(v.y);
            B_lds[(n4 * 4 + 2) * LDP + kk] = f2bf(v.z);
            B_lds[(n4 * 4 + 3) * LDP + kk] = f2bf(v.w);
        }
        __syncthreads();

        bf16x8 af[4], bf[4];
#pragma unroll
        for (int mt = 0; mt < 4; ++mt)
            af[mt] = *(const bf16x8*)&A_lds[(mt * 16 + m16) * LDP + quad * 8];
#pragma unroll
        for (int nt = 0; nt < 4; ++nt)
            bf[nt] = *(const bf16x8*)&B_lds[(w * 64 + nt * 16 + m16) * LDP + quad * 8];
#pragma unroll
        for (int mt = 0; mt < 4; ++mt)
#pragma unroll
            for (int nt = 0; nt < 4; ++nt)
                acc[mt][nt] = __builtin_amdgcn_mfma_f32_16x16x32_bf16(
                    af[mt], bf[nt], acc[mt][nt], 0, 0, 0);
        __syncthreads();
    }

#pragma unroll
    for (int nt = 0; nt < 4; ++nt) {
        const int col = w * 64 + nt * 16 + m16;
        const float bias = b[col];
#pragma unroll
        for (int mt = 0; mt < 4; ++mt) {
#pragma unroll
            for (int r = 0; r < 4; ++r) {
                const int row = row0 + mt * 16 + quad * 4 + r;
                if (row < N_NODES)
                    H[(size_t)row * 256 + col] = __float2bfloat16(acc[mt][nt][r] + bias);
            }
        }
    }
}

// ---------------------------------------------------------------------------
// CSR gather v4 (proven at ~66-70 us): dual-group lanes. lane = (gi=lane>>5,
// fp = lane&31). Each lane loads a dword of H (2 bf16 features); the two wave
// halves process TWO 8-edge groups per iteration. Metadata staged in a
// wave-private LDS slice (broadcast ds_read in the inner loop). Group fold is
// one shfl_xor(32) per accumulator; lanes 0-31 store float2.
// grid = (ceil(N/64), HOPS)
// ---------------------------------------------------------------------------
__global__ __launch_bounds__(256) void csr_gather_kernel(const __hip_bfloat16* __restrict__ H,
                                                         const int* __restrict__ offsets,
                                                         const int2* __restrict__ epk,
                                                         float* __restrict__ out) {
    __shared__ int2 meta[4][MCAP + 16];             // 16.9 KB
    const int t = threadIdx.x;
    const int f = t & 63;
    const int w = t >> 6;
    const int hop = blockIdx.y;
    const int row0w = blockIdx.x * 64 + w * 16;
    if (row0w >= N_NODES) return;                   // no __syncthreads below
    const int bin0 = hop * N_NODES + row0w;

    int off_l = 0;
    if (f <= 16) off_l = offsets[bin0 + f];        // 17 rowptr entries per wave
    const int s0w = __builtin_amdgcn_readlane(off_l, 0);
    const int s1w = __builtin_amdgcn_readlane(off_l, 16);
    const int cnt = s1w - s0w;

    if (cnt <= MCAP) {
        const int gi = f >> 5;                     // edge sub-group 0/1
        const int fp = f & 31;                     // feature-pair index
        const char* Hb = (const char*)H + hop * 128 + fp * 4;
        float* outp = out + (size_t)row0w * 256 + hop * 64 + fp * 2;

        int2* M = meta[w];
        for (int i = f; i < cnt; i += 64) M[i] = epk[s0w + i];
        if (f < 16) M[cnt + f] = make_int2(0, 0);  // zero-pad tail groups
        // wave-local LDS: in-order within wave, no barrier needed

        for (int r = 0; r < 16; ++r) {
            const int s  = __builtin_amdgcn_readlane(off_l, r) - s0w;
            const int e2 = __builtin_amdgcn_readlane(off_l, r + 1) - s0w;
            float aLo = 0.f, aHi = 0.f;
            for (int g = s; g < e2; g += 16) {
                int2 mm[8];
#pragma unroll
                for (int j = 0; j < 8; ++j) mm[j] = M[g + gi * 8 + j];
                unsigned hv[8];
#pragma unroll
                for (int j = 0; j < 8; ++j) {
                    // col*512 + hop*128 + fp*4: dword = features {2fp, 2fp+1}
                    hv[j] = *(const unsigned*)(Hb + ((size_t)(unsigned)mm[j].x << 9));
                }
#pragma unroll
                for (int j = 0; j < 8; ++j) {
                    const float vj = (g + gi * 8 + j < e2) ? __int_as_float(mm[j].y) : 0.f;
                    aLo = fmaf(vj, __uint_as_float(hv[j] << 16), aLo);
                    aHi = fmaf(vj, __uint_as_float(hv[j] & 0xffff0000u), aHi);
                }
            }
            aLo += __shfl_xor(aLo, 32, 64);        // fold the two edge groups
            aHi += __shfl_xor(aHi, 32, 64);
            aLo = aLo > 0.f ? aLo : __expf(aLo) - 1.f;
            aHi = aHi > 0.f ? aHi : __expf(aHi) - 1.f;
            if (f < 32)
                *(float2*)(outp + (size_t)r * 256) = make_float2(aLo, aHi);
        }
    } else {
        // Fallback (cnt > MCAP, ~16-sigma tail): readlane path.
        const unsigned short* Hf = (const unsigned short*)H + hop * 64 + f;
        float* outp = out + (size_t)row0w * 256 + hop * 64 + f;
        for (int r = 0; r < 16; ++r) {
            const int s  = __builtin_amdgcn_readlane(off_l, r);
            const int e2 = __builtin_amdgcn_readlane(off_l, r + 1);
            float acc = 0.f;
            int e = s;
            for (; e + 8 <= e2; e += 8) {
                const int2 m = epk[e + (f & 7)];
                float h8[8];
#pragma unroll
                for (int j = 0; j < 8; ++j) {
                    const int col = __builtin_amdgcn_readlane(m.x, j);
                    h8[j] = __uint_as_float((unsigned)Hf[(size_t)col << 8] << 16);
                }
#pragma unroll
                for (int j = 0; j < 8; ++j) {
                    const float val =
                        __uint_as_float((unsigned)__builtin_amdgcn_readlane(m.y, j));
                    acc = fmaf(val, h8[j], acc);
                }
            }
            if (e < e2) {
                const int2 m = epk[e + (f & 7)];
                const int rem = e2 - e;
                for (int j = 0; j < rem; ++j) {
                    const int col = __builtin_amdgcn_readlane(m.x, j);
                    const float val =
                        __uint_as_float((unsigned)__builtin_amdgcn_readlane(m.y, j));
                    acc = fmaf(val, __uint_as_float((unsigned)Hf[(size_t)col << 8] << 16),
                               acc);
                }
            }
            acc = acc > 0.f ? acc : __expf(acc) - 1.f;
            outp[(size_t)r * 256] = acc;
        }
    }
}

// ---------------------------------------------------------------------------
// Fallback path (atomic scatter) if workspace is too small.
// ---------------------------------------------------------------------------
#define EPW 8
__global__ __launch_bounds__(256) void scatter_kernel(const __hip_bfloat16* __restrict__ H,
                                                      const int* __restrict__ rows,
                                                      const int* __restrict__ cols,
                                                      const float* __restrict__ vals,
                                                      float* __restrict__ out) {
    const int lane = threadIdx.x & 63;
    const int wid = __builtin_amdgcn_readfirstlane(threadIdx.x >> 6);
    const int hop = blockIdx.y;
    const int e0 = (blockIdx.x * 4 + wid) * EPW;
    const int base = hop * NEDGES;
    const int hoff = hop * 64 + lane;
#pragma unroll
    for (int i = 0; i < EPW; ++i) {
        const int e = e0 + i;
        const int r = rows[base + e];
        const int c = cols[base + e];
        const float v = vals[base + e];
        unsafeAtomicAdd(&out[(size_t)r * 256 + hoff],
                        v * __bfloat162float(H[(size_t)c * 256 + hoff]));
    }
}

__global__ __launch_bounds__(256) void elu_kernel(float* __restrict__ out, int n4) {
    const int i = blockIdx.x * 256 + threadIdx.x;
    if (i < n4) {
        float4 v = ((float4*)out)[i];
        v.x = v.x > 0.f ? v.x : expf(v.x) - 1.f;
        v.y = v.y > 0.f ? v.y : expf(v.y) - 1.f;
        v.z = v.z > 0.f ? v.z : expf(v.z) - 1.f;
        v.w = v.w > 0.f ? v.w : expf(v.w) - 1.f;
        ((float4*)out)[i] = v;
    }
}

extern "C" void kernel_launch(void* const* d_in, const int* in_sizes, int n_in,
                              void* d_out, int out_size, void* d_ws, size_t ws_size,
                              hipStream_t stream) {
    const float* x        = (const float*)d_in[0];
    const float* W        = (const float*)d_in[1];
    const float* b        = (const float*)d_in[2];
    const int*   adj_rows = (const int*)d_in[3];
    const int*   adj_cols = (const int*)d_in[4];
    const float* adj_vals = (const float*)d_in[5];
    float* out = (float*)d_out;

    // Workspace layout (~53.7 MB)
    char* w = (char*)d_ws;
    size_t off = 0;
    __hip_bfloat16* H = (__hip_bfloat16*)(w + off);
    off += (size_t)N_NODES * 256 * 2;                                          // 25.6 MB
    int2*  partbuf = (int2*)(w + off);  off += (size_t)HOPS * NEDGES * 8;      // 25.6 MB
    int*   offsets = (int*)(w + off);   off += (((size_t)(NBINS + 1)) * 4 + 255) & ~255ull;
    int*   cnt     = (int*)(w + off);   off += ((size_t)NBINS * 4 + 255) & ~255ull;
    int*   cursor  = (int*)(w + off);   off += ((size_t)NBINS * 4 + 255) & ~255ull;
    int*   tsum    = (int*)(w + off);   off += ((size_t)NTILE * 4 + 255) & ~255ull;
    unsigned short* Wt = (unsigned short*)(w + off);
    off += (size_t)HOPS * NFEAT * NHID * 2;                                    // 128 KB
    const bool use_sorted = (ws_size >= off);

    // Alias: Xbf lives in the partbuf region (dead until place_kernel).
    unsigned short* Xbf = (unsigned short*)partbuf;

    if (use_sorted) {
        hipMemsetAsync(cnt, 0, (size_t)NBINS * 4, stream);
        // K1: rhist || castw || castx (independent)
        prep_kernel<<<PREP_TOTAL, 256, 0, stream>>>(x, Xbf, W, Wt, adj_rows, cnt);
        // K2: scanA (blocks 0..195) || gemm (blocks 196..977)
        gemm_scan_kernel<<<NTILE + NGBLK, 256, 0, stream>>>(Xbf, Wt, b, H,
                                                            cnt, offsets, tsum);
        // K3: fixup (tile bases -> final offsets + cursor)
        fixup_kernel<<<NTILE, 256, 0, stream>>>(tsum, offsets, cursor);
        // K4: direct placement (replaces partition + fsort)
        place_kernel<<<dim3(NCHUNK, HOPS), 256, 0, stream>>>(adj_rows, adj_cols,
                                                             adj_vals, cursor, partbuf);
        // K5: gather
        csr_gather_kernel<<<dim3((N_NODES + 63) / 64, HOPS), 256, 0, stream>>>(
            H, offsets, partbuf, out);
    } else {
        gemm_mfma_kernel<<<NGBLK, 256, 0, stream>>>(x, W, b, H);
        hipMemsetAsync(d_out, 0, (size_t)out_size * sizeof(float), stream);
        scatter_kernel<<<dim3(NEDGES / (4 * EPW), HOPS), 256, 0, stream>>>(
            H, adj_rows, adj_cols, adj_vals, out);
        elu_kernel<<<(out_size / 4 + 255) / 256, 256, 0, stream>>>(out, out_size / 4);
    }
}

// Round 8
// 315.827 us; speedup vs baseline: 1.6828x; 1.6828x over previous
//
#include <hip/hip_runtime.h>
#include <hip/hip_bf16.h>
#include <math.h>

#define N_NODES 50000
#define NFEAT 256
#define NHID 64
#define HOPS 4
#define NEDGES 800000

#define BROWS 64                     // rows per bucket == rows per gather block
#define NBUCK 782                    // ceil(50000/64) buckets per hop
#define NBK_ALL (HOPS * NBUCK)       // 3128
#define CHUNK 4096                   // edges per partition block
#define NCHUNK ((NEDGES + CHUNK - 1) / CHUNK)  // 196
#define CAP 2048                     // sortgather tile cap (mean 1024; fsort@2048 passed => max <= 2048)

// MFMA GEMM tile config
#define GM 64                        // rows per block
#define LDP 40                       // LDS k-stride in bf16 (80 B: 16B-aligned, 2-way banks)
#define NGBLK ((N_NODES + GM - 1) / GM)   // 782

// prep fusion block ranges (castx removed: gemm reads x f32 directly)
#define PREP_BHIST (NCHUNK * HOPS)                            // 784
#define PREP_TOTAL (PREP_BHIST + 256)                         // 1040

typedef short bf16x8 __attribute__((ext_vector_type(8)));
typedef float f32x4 __attribute__((ext_vector_type(4)));

static __device__ __forceinline__ unsigned short f2bf(float f) {
    __hip_bfloat16 h = __float2bfloat16(f);
    return *reinterpret_cast<unsigned short*>(&h);
}

// ---------------------------------------------------------------------------
// K1: fused prep = bhist (blocks 0..783) || castw (784..1039).
// castw writes Wt in [ks][gcol][kk] layout so each GEMM ks-tile is a
// contiguous 16 KB block (coalesced B-staging; proven round 6).
// ---------------------------------------------------------------------------
__global__ __launch_bounds__(256) void prep_kernel(const float* __restrict__ W,
                                                   unsigned short* __restrict__ Wt,
                                                   const int* __restrict__ rows,
                                                   int* __restrict__ bucket_cnt) {
    __shared__ int h[NBUCK];                       // 3.1 KB, bhist branch only
    const int bid = blockIdx.x;
    const int t = threadIdx.x;

    if (bid < PREP_BHIST) {
        // ---- bhist: coarse 64-row bucket histogram ----
        for (int i = t; i < NBUCK; i += 256) h[i] = 0;
        __syncthreads();
        const int hop = bid / NCHUNK;
        const int e0 = (bid % NCHUNK) * CHUNK;
        const int n = min(CHUNK, NEDGES - e0);
        const size_t base = (size_t)hop * NEDGES + e0;
        for (int i = t; i < n; i += 256) {
            atomicAdd(&h[rows[base + i] >> 6], 1);
        }
        __syncthreads();
        for (int i = t; i < NBUCK; i += 256) {
            if (h[i]) atomicAdd(&bucket_cnt[hop * NBUCK + i], h[i]);
        }
    } else {
        // ---- castw: W [hop][k][c] f32 -> Wt [k>>5][hop*64+c][k&31] bf16 ----
        const int idx = (bid - PREP_BHIST) * 256 + t;      // 65536 exact
        const int hop = idx >> 14;
        const int k = (idx >> 6) & 255;
        const int c = idx & 63;
        Wt[(size_t)(k >> 5) * (256 * 32) + (hop * 64 + c) * 32 + (k & 31)] = f2bf(W[idx]);
    }
}

// ---------------------------------------------------------------------------
// K2: fused gemm (blocks 1..782) || bscan (block 0).
// A staged directly from f32 x with inline cvt (round-0 proven pattern);
// B from the ks-contiguous Wt tile (coalesced, round-6 proven).
// ---------------------------------------------------------------------------
#define SCAN_V ((NBK_ALL + 255) / 256)   // 13
__global__ __launch_bounds__(256) void gemm_scan_kernel(const float* __restrict__ x,
                                                        const unsigned short* __restrict__ Wt,
                                                        const float* __restrict__ b,
                                                        __hip_bfloat16* __restrict__ H,
                                                        const int* __restrict__ cnt,
                                                        int* __restrict__ start,
                                                        int* __restrict__ cursor) {
    __shared__ char smem[GM * LDP * 2 + 256 * LDP * 2];   // 25600 B
    const int t = threadIdx.x;

    if (blockIdx.x == 0) {
        // ---- bscan: exclusive scan of 3128 bucket counts ----
        int* s = (int*)smem;
        int v[SCAN_V];
        int tsum = 0;
#pragma unroll
        for (int i = 0; i < SCAN_V; ++i) {
            const int idx = t * SCAN_V + i;
            v[i] = (idx < NBK_ALL) ? cnt[idx] : 0;
            tsum += v[i];
        }
        s[t] = tsum;
        __syncthreads();
        for (int off = 1; off < 256; off <<= 1) {
            const int a = (t >= off) ? s[t - off] : 0;
            __syncthreads();
            s[t] += a;
            __syncthreads();
        }
        int run = s[t] - tsum;
#pragma unroll
        for (int i = 0; i < SCAN_V; ++i) {
            const int idx = t * SCAN_V + i;
            if (idx < NBK_ALL) {
                start[idx] = run;
                cursor[idx] = run;
                run += v[i];
            }
        }
        if (t == 255) start[NBK_ALL] = run;
        return;
    }

    // ---- gemm: H[n][c] = bf16( sum_k x[n][k]*W[k][c] + b[c] ) ----
    unsigned short* A_lds = (unsigned short*)smem;                  // GM*LDP
    unsigned short* B_lds = (unsigned short*)(smem + GM * LDP * 2); // 256*LDP

    const int lane = t & 63;
    const int w = t >> 6;
    const int quad = lane >> 4;
    const int m16 = lane & 15;
    const int row0 = (blockIdx.x - 1) * GM;

    f32x4 acc[4][4];
#pragma unroll
    for (int mt = 0; mt < 4; ++mt)
#pragma unroll
        for (int nt = 0; nt < 4; ++nt) acc[mt][nt] = (f32x4){0.f, 0.f, 0.f, 0.f};

    for (int ks = 0; ks < 8; ++ks) {
        const int k0 = ks * 32;
        // A: f32 -> bf16 inline, 2 x float4 per thread (round-0 pattern)
#pragma unroll
        for (int it = 0; it < 2; ++it) {
            const int i = t + it * 256;
            const int r = i >> 3;
            const int kq = (i & 7) * 4;
            float4 v = make_float4(0.f, 0.f, 0.f, 0.f);
            if (row0 + r < N_NODES)
                v = *(const float4*)&x[(size_t)(row0 + r) * NFEAT + k0 + kq];
            unsigned short* d = &A_lds[r * LDP + kq];
            d[0] = f2bf(v.x); d[1] = f2bf(v.y); d[2] = f2bf(v.z); d[3] = f2bf(v.w);
        }
        // B: contiguous 16 KB ks-tile, 4 x 16 B per thread, fully coalesced
#pragma unroll
        for (int it = 0; it < 4; ++it) {
            const int i = t + it * 256;
            const bf16x8 v = *(const bf16x8*)&Wt[(size_t)ks * (256 * 32) + (size_t)i * 8];
            *(bf16x8*)&B_lds[(i >> 2) * LDP + (i & 3) * 8] = v;
        }
        __syncthreads();

        bf16x8 af[4], bf[4];
#pragma unroll
        for (int mt = 0; mt < 4; ++mt)
            af[mt] = *(const bf16x8*)&A_lds[(mt * 16 + m16) * LDP + quad * 8];
#pragma unroll
        for (int nt = 0; nt < 4; ++nt)
            bf[nt] = *(const bf16x8*)&B_lds[(w * 64 + nt * 16 + m16) * LDP + quad * 8];
#pragma unroll
        for (int mt = 0; mt < 4; ++mt)
#pragma unroll
            for (int nt = 0; nt < 4; ++nt)
                acc[mt][nt] = __builtin_amdgcn_mfma_f32_16x16x32_bf16(
                    af[mt], bf[nt], acc[mt][nt], 0, 0, 0);
        __syncthreads();
    }

#pragma unroll
    for (int nt = 0; nt < 4; ++nt) {
        const int col = w * 64 + nt * 16 + m16;
        const float bias = b[col];
#pragma unroll
        for (int mt = 0; mt < 4; ++mt) {
#pragma unroll
            for (int r = 0; r < 4; ++r) {
                const int row = row0 + mt * 16 + quad * 4 + r;
                if (row < N_NODES)
                    H[(size_t)row * 256 + col] = __float2bfloat16(acc[mt][nt][r] + bias);
            }
        }
    }
}

// ---------------------------------------------------------------------------
// Legacy f32-input GEMM (fallback path only).
// ---------------------------------------------------------------------------
__global__ __launch_bounds__(256) void gemm_mfma_kernel(const float* __restrict__ x,
                                                        const float* __restrict__ W,
                                                        const float* __restrict__ b,
                                                        __hip_bfloat16* __restrict__ H) {
    __shared__ unsigned short A_lds[GM * LDP];
    __shared__ unsigned short B_lds[256 * LDP];

    const int t = threadIdx.x;
    const int lane = t & 63;
    const int w = t >> 6;
    const int quad = lane >> 4;
    const int m16 = lane & 15;
    const int row0 = blockIdx.x * GM;

    f32x4 acc[4][4];
#pragma unroll
    for (int mt = 0; mt < 4; ++mt)
#pragma unroll
        for (int nt = 0; nt < 4; ++nt) acc[mt][nt] = (f32x4){0.f, 0.f, 0.f, 0.f};

    for (int ks = 0; ks < 8; ++ks) {
        const int k0 = ks * 32;
#pragma unroll
        for (int it = 0; it < 2; ++it) {
            const int i = t + it * 256;
            const int r = i >> 3;
            const int kq = (i & 7) * 4;
            float4 v = make_float4(0.f, 0.f, 0.f, 0.f);
            if (row0 + r < N_NODES)
                v = *(const float4*)&x[(size_t)(row0 + r) * NFEAT + k0 + kq];
            unsigned short* d = &A_lds[r * LDP + kq];
            d[0] = f2bf(v.x); d[1] = f2bf(v.y); d[2] = f2bf(v.z); d[3] = f2bf(v.w);
        }
#pragma unroll
        for (int it = 0; it < 8; ++it) {
            const int i = t + it * 256;
            const int n4 = i & 63;
            const int kk = i >> 6;
            const int hop = n4 >> 4;
            const int j = (n4 & 15) * 4;
            const float4 v = *(const float4*)&W[(size_t)hop * (NFEAT * NHID)
                                                + (size_t)(k0 + kk) * NHID + j];
            B_lds[(n4 * 4 + 0) * LDP + kk] = f2bf(v.x);
            B_lds[(n4 * 4 + 1) * LDP + kk] = f2bf(v.y);
            B_lds[(n4 * 4 + 2) * LDP + kk] = f2bf(v.z);
            B_lds[(n4 * 4 + 3) * LDP + kk] = f2bf(v.w);
        }
        __syncthreads();

        bf16x8 af[4], bf[4];
#pragma unroll
        for (int mt = 0; mt < 4; ++mt)
            af[mt] = *(const bf16x8*)&A_lds[(mt * 16 + m16) * LDP + quad * 8];
#pragma unroll
        for (int nt = 0; nt < 4; ++nt)
            bf[nt] = *(const bf16x8*)&B_lds[(w * 64 + nt * 16 + m16) * LDP + quad * 8];
#pragma unroll
        for (int mt = 0; mt < 4; ++mt)
#pragma unroll
            for (int nt = 0; nt < 4; ++nt)
                acc[mt][nt] = __builtin_amdgcn_mfma_f32_16x16x32_bf16(
                    af[mt], bf[nt], acc[mt][nt], 0, 0, 0);
        __syncthreads();
    }

#pragma unroll
    for (int nt = 0; nt < 4; ++nt) {
        const int col = w * 64 + nt * 16 + m16;
        const float bias = b[col];
#pragma unroll
        for (int mt = 0; mt < 4; ++mt) {
#pragma unroll
            for (int r = 0; r < 4; ++r) {
                const int row = row0 + mt * 16 + quad * 4 + r;
                if (row < N_NODES)
                    H[(size_t)row * 256 + col] = __float2bfloat16(acc[mt][nt][r] + bias);
            }
        }
    }
}

// ---------------------------------------------------------------------------
// K3: coarse partition into 64-row buckets via LDS counting sort (EXACT
// round-6 code, 71.5 us known). Payload: {(row<<16)|col, float_bits(val)}.
// grid = (NCHUNK, HOPS)
// ---------------------------------------------------------------------------
__global__ __launch_bounds__(256) void partition_kernel(const int* __restrict__ rows,
                                                        const int* __restrict__ cols,
                                                        const float* __restrict__ vals,
                                                        int* __restrict__ cursor,
                                                        int2* __restrict__ partbuf) {
    __shared__ int2 pay[CHUNK];                     // 32 KB
    __shared__ int h[NBUCK], excl[NBUCK], gbase[NBUCK], lcur[NBUCK];  // 12.5 KB
    __shared__ int s[256];
    const int t = threadIdx.x;
    const int hop = blockIdx.y;
    const int e0 = blockIdx.x * CHUNK;
    const int n = min(CHUNK, NEDGES - e0);
    const size_t base = (size_t)hop * NEDGES + e0;

    for (int i = t; i < NBUCK; i += 256) h[i] = 0;
    __syncthreads();

    int myrow[CHUNK / 256];
#pragma unroll
    for (int j = 0; j < CHUNK / 256; ++j) {
        const int i = t + j * 256;
        if (i < n) {
            const int r = rows[base + i];
            myrow[j] = r;
            atomicAdd(&h[r >> 6], 1);
        }
    }
    __syncthreads();

    int pv[4];
    int tsum = 0;
#pragma unroll
    for (int i = 0; i < 4; ++i) {
        const int idx = t * 4 + i;
        pv[i] = (idx < NBUCK) ? h[idx] : 0;
        tsum += pv[i];
    }
    s[t] = tsum;
    __syncthreads();
    for (int off = 1; off < 256; off <<= 1) {
        const int a = (t >= off) ? s[t - off] : 0;
        __syncthreads();
        s[t] += a;
        __syncthreads();
    }
    int run = s[t] - tsum;
#pragma unroll
    for (int i = 0; i < 4; ++i) {
        const int idx = t * 4 + i;
        if (idx < NBUCK) {
            excl[idx] = run;
            lcur[idx] = run;
            gbase[idx] = pv[i] ? atomicAdd(&cursor[hop * NBUCK + idx], pv[i]) : 0;
            run += pv[i];
        }
    }
    __syncthreads();

#pragma unroll
    for (int j = 0; j < CHUNK / 256; ++j) {
        const int i = t + j * 256;
        if (i < n) {
            const int r = myrow[j];
            const int c = cols[base + i];
            const float v = vals[base + i];
            const int pos = atomicAdd(&lcur[r >> 6], 1);
            pay[pos] = make_int2((r << 16) | c, __float_as_int(v));
        }
    }
    __syncthreads();

    for (int i = t; i < n; i += 256) {
        const int2 p = pay[i];
        const int bk = ((unsigned)p.x) >> 22;       // row >> 6
        partbuf[gbase[bk] + (i - excl[bk])] = p;
    }
}

// ---------------------------------------------------------------------------
// K4: sortgather (fsort folded into gather). Block = one (bucket, hop):
// per tile (cap 2048): stage bucket edges to registers + LDS row-histogram
// (INT atomics, native) -> scan -> counting-scatter into sorted LDS M with
// rowptr -> proven dual-group inner loop (lane = (gi,fp), 2 bf16 feats per
// lane, broadcast ds_read metadata, shfl_xor fold). Accumulators aL/aH[16]
// statically indexed -> live across tiles -> any cnt is handled correctly.
// grid = (NBUCK, HOPS)
// ---------------------------------------------------------------------------
__global__ __launch_bounds__(256) void sortgather_kernel(const __hip_bfloat16* __restrict__ H,
                                                         const int* __restrict__ start,
                                                         const int2* __restrict__ partbuf,
                                                         float* __restrict__ out) {
    __shared__ int2 M[CAP + 16];                    // 16.5 KB sorted {col,val}
    __shared__ int rowptr[BROWS + 1];
    __shared__ int h[BROWS], cur[BROWS];
    __shared__ int s[256];
    const int t = threadIdx.x;
    const int f = t & 63;
    const int w = t >> 6;
    const int gi = f >> 5;                          // edge sub-group 0/1
    const int fp = f & 31;                          // feature-pair index
    const int hop = blockIdx.y;
    const int bucket = blockIdx.x;
    const int g = hop * NBUCK + bucket;
    const int s0 = start[g];
    const int cnt = start[g + 1] - s0;
    const int row0w = bucket * BROWS + w * 16;

    const char* Hb = (const char*)H + hop * 128 + fp * 4;

    float aL[16], aH[16];
#pragma unroll
    for (int r = 0; r < 16; ++r) { aL[r] = 0.f; aH[r] = 0.f; }

    for (int base = 0; base < cnt; base += CAP) {
        const int n = min(CAP, cnt - base);
        if (t < BROWS) h[t] = 0;
        __syncthreads();

        // pass A: coalesced load to registers + row histogram (int LDS atomics)
        int2 myp[CAP / 256];
#pragma unroll
        for (int k = 0; k < CAP / 256; ++k) {
            const int i = t + k * 256;
            if (i < n) {
                const int2 p = partbuf[s0 + base + i];
                myp[k] = p;
                atomicAdd(&h[((unsigned)p.x >> 16) & (BROWS - 1)], 1);
            }
        }
        __syncthreads();

        // scan h[64] -> rowptr (exclusive), cur
        const int hv = (t < BROWS) ? h[t] : 0;
        s[t] = hv;
        __syncthreads();
        for (int off = 1; off < BROWS; off <<= 1) {
            const int a = (t >= off) ? s[t - off] : 0;
            __syncthreads();
            s[t] += a;
            __syncthreads();
        }
        if (t < BROWS) {
            rowptr[t] = s[t] - hv;
            cur[t] = s[t] - hv;
        }
        if (t == 0) rowptr[BROWS] = n;
        __syncthreads();

        // pass B: counting-scatter into sorted M ({col, val})
#pragma unroll
        for (int k = 0; k < CAP / 256; ++k) {
            const int i = t + k * 256;
            if (i < n) {
                const int2 p = myp[k];
                const int rl = ((unsigned)p.x >> 16) & (BROWS - 1);
                const int pos = atomicAdd(&cur[rl], 1);
                M[pos] = make_int2(p.x & 0xFFFF, p.y);
            }
        }
        if (t < 16) M[n + t] = make_int2(0, 0);     // pad for tail predication
        __syncthreads();

        // compute: wave w owns rows w*16..w*16+15
        int off_l = 0;
        if (f <= 16) off_l = rowptr[w * 16 + f];
#pragma unroll
        for (int r = 0; r < 16; ++r) {
            const int sE = __builtin_amdgcn_readlane(off_l, r);
            const int e2 = __builtin_amdgcn_readlane(off_l, r + 1);
            for (int gg = sE; gg < e2; gg += 16) {
                int2 mm[8];
#pragma unroll
                for (int j = 0; j < 8; ++j) mm[j] = M[gg + gi * 8 + j];
                unsigned hv8[8];
#pragma unroll
                for (int j = 0; j < 8; ++j)
                    hv8[j] = *(const unsigned*)(Hb + ((size_t)(unsigned)mm[j].x << 9));
#pragma unroll
                for (int j = 0; j < 8; ++j) {
                    const float vj = (gg + gi * 8 + j < e2) ? __int_as_float(mm[j].y) : 0.f;
                    aL[r] = fmaf(vj, __uint_as_float(hv8[j] << 16), aL[r]);
                    aH[r] = fmaf(vj, __uint_as_float(hv8[j] & 0xffff0000u), aH[r]);
                }
            }
        }
        __syncthreads();                            // M stable until next tile's pass B
    }

    // epilogue: fold halves, ELU, store float2 from lanes 0-31
    float* outp = out + (size_t)row0w * 256 + hop * 64 + fp * 2;
#pragma unroll
    for (int r = 0; r < 16; ++r) {
        float lo = aL[r] + __shfl_xor(aL[r], 32, 64);
        float hi = aH[r] + __shfl_xor(aH[r], 32, 64);
        lo = lo > 0.f ? lo : __expf(lo) - 1.f;
        hi = hi > 0.f ? hi : __expf(hi) - 1.f;
        if (f < 32 && row0w + r < N_NODES)
            *(float2*)(outp + (size_t)r * 256) = make_float2(lo, hi);
    }
}

// ---------------------------------------------------------------------------
// Fallback path (atomic scatter) if workspace is too small.
// ---------------------------------------------------------------------------
#define EPW 8
__global__ __launch_bounds__(256) void scatter_kernel(const __hip_bfloat16* __restrict__ H,
                                                      const int* __restrict__ rows,
                                                      const int* __restrict__ cols,
                                                      const float* __restrict__ vals,
                                                      float* __restrict__ out) {
    const int lane = threadIdx.x & 63;
    const int wid = __builtin_amdgcn_readfirstlane(threadIdx.x >> 6);
    const int hop = blockIdx.y;
    const int e0 = (blockIdx.x * 4 + wid) * EPW;
    const int base = hop * NEDGES;
    const int hoff = hop * 64 + lane;
#pragma unroll
    for (int i = 0; i < EPW; ++i) {
        const int e = e0 + i;
        const int r = rows[base + e];
        const int c = cols[base + e];
        const float v = vals[base + e];
        unsafeAtomicAdd(&out[(size_t)r * 256 + hoff],
                        v * __bfloat162float(H[(size_t)c * 256 + hoff]));
    }
}

__global__ __launch_bounds__(256) void elu_kernel(float* __restrict__ out, int n4) {
    const int i = blockIdx.x * 256 + threadIdx.x;
    if (i < n4) {
        float4 v = ((float4*)out)[i];
        v.x = v.x > 0.f ? v.x : expf(v.x) - 1.f;
        v.y = v.y > 0.f ? v.y : expf(v.y) - 1.f;
        v.z = v.z > 0.f ? v.z : expf(v.z) - 1.f;
        v.w = v.w > 0.f ? v.w : expf(v.w) - 1.f;
        ((float4*)out)[i] = v;
    }
}

extern "C" void kernel_launch(void* const* d_in, const int* in_sizes, int n_in,
                              void* d_out, int out_size, void* d_ws, size_t ws_size,
                              hipStream_t stream) {
    const float* x        = (const float*)d_in[0];
    const float* W        = (const float*)d_in[1];
    const float* b        = (const float*)d_in[2];
    const int*   adj_rows = (const int*)d_in[3];
    const int*   adj_cols = (const int*)d_in[4];
    const float* adj_vals = (const float*)d_in[5];
    float* out = (float*)d_out;

    // Workspace layout (~51.4 MB)
    char* w = (char*)d_ws;
    size_t off = 0;
    __hip_bfloat16* H = (__hip_bfloat16*)(w + off);
    off += (size_t)N_NODES * 256 * 2;                                          // 25.6 MB
    int2*  partbuf    = (int2*)(w + off);  off += (size_t)HOPS * NEDGES * 8;   // 25.6 MB
    int*   bucket_cnt = (int*)(w + off);   off += ((size_t)NBK_ALL * 4 + 255) & ~255ull;
    int*   bstart     = (int*)(w + off);   off += (((size_t)NBK_ALL + 1) * 4 + 255) & ~255ull;
    int*   bcursor    = (int*)(w + off);   off += ((size_t)NBK_ALL * 4 + 255) & ~255ull;
    unsigned short* Wt = (unsigned short*)(w + off);
    off += (size_t)HOPS * NFEAT * NHID * 2;                                    // 128 KB
    const bool use_sorted = (ws_size >= off);

    if (use_sorted) {
        hipMemsetAsync(bucket_cnt, 0, (size_t)NBK_ALL * 4, stream);
        // K1: bhist || castw
        prep_kernel<<<PREP_TOTAL, 256, 0, stream>>>(W, Wt, adj_rows, bucket_cnt);
        // K2: bscan (block 0) || gemm (blocks 1..782), A from f32 x directly
        gemm_scan_kernel<<<NGBLK + 1, 256, 0, stream>>>(x, Wt, b, H,
                                                        bucket_cnt, bstart, bcursor);
        // K3: coarse partition (round-6 exact)
        partition_kernel<<<dim3(NCHUNK, HOPS), 256, 0, stream>>>(adj_rows, adj_cols,
                                                                 adj_vals, bcursor, partbuf);
        // K4: fused sort + gather (fsort eliminated)
        sortgather_kernel<<<dim3(NBUCK, HOPS), 256, 0, stream>>>(H, bstart, partbuf, out);
    } else {
        gemm_mfma_kernel<<<NGBLK, 256, 0, stream>>>(x, W, b, H);
        hipMemsetAsync(d_out, 0, (size_t)out_size * sizeof(float), stream);
        scatter_kernel<<<dim3(NEDGES / (4 * EPW), HOPS), 256, 0, stream>>>(
            H, adj_rows, adj_cols, adj_vals, out);
        elu_kernel<<<(out_size / 4 + 255) / 256, 256, 0, stream>>>(out, out_size / 4);
    }
}

// Round 9
// 305.923 us; speedup vs baseline: 1.7373x; 1.0324x over previous
//
#include <hip/hip_runtime.h>
#include <hip/hip_bf16.h>
#include <math.h>

#define N_NODES 50000
#define NFEAT 256
#define NHID 64
#define HOPS 4
#define NEDGES 800000

#define BROWS 64                     // rows per bucket == rows per gather block
#define NBUCK 782                    // ceil(50000/64) buckets per hop
#define NBK_ALL (HOPS * NBUCK)       // 3128
#define CHUNK 4096                   // edges per partition block
#define NCHUNK ((NEDGES + CHUNK - 1) / CHUNK)  // 196
#define CAP 2048                     // sortgather tile cap (mean 1024; fsort@2048 passed => max <= 2048)

// MFMA GEMM tile config
#define GM 64                        // rows per block
#define LDP 40                       // LDS k-stride in bf16 (80 B: 16B-aligned, 2-way banks)
#define NGBLK ((N_NODES + GM - 1) / GM)   // 782

// prep fusion block ranges
#define PREP_BHIST (NCHUNK * HOPS)                            // 784
#define PREP_CASTW_END (PREP_BHIST + 256)                     // 1040
#define PREP_CASTX_BLKS ((N_NODES * NFEAT / 8) / 256)         // 6250 (exact)
#define PREP_TOTAL (PREP_CASTW_END + PREP_CASTX_BLKS)         // 7290

typedef short bf16x8 __attribute__((ext_vector_type(8)));
typedef float f32x4 __attribute__((ext_vector_type(4)));

static __device__ __forceinline__ unsigned short f2bf(float f) {
    __hip_bfloat16 h = __float2bfloat16(f);
    return *reinterpret_cast<unsigned short*>(&h);
}

// ---------------------------------------------------------------------------
// K1: fused prep = bhist (blocks 0..783) || castw (784..1039) ||
//     castx (1040..7289).
// castw writes Wt in [ks][gcol][kk] layout -> contiguous 16 KB GEMM B-tiles
// (coalesced staging, proven round 6). castx precasts x to bf16 (proven
// round 2/6: saves ~25 us vs inline f32 staging in the GEMM).
// ---------------------------------------------------------------------------
__global__ __launch_bounds__(256) void prep_kernel(const float* __restrict__ x,
                                                   unsigned short* __restrict__ Xbf,
                                                   const float* __restrict__ W,
                                                   unsigned short* __restrict__ Wt,
                                                   const int* __restrict__ rows,
                                                   int* __restrict__ bucket_cnt) {
    __shared__ int h[NBUCK];                       // 3.1 KB, bhist branch only
    const int bid = blockIdx.x;
    const int t = threadIdx.x;

    if (bid < PREP_BHIST) {
        // ---- bhist: coarse 64-row bucket histogram ----
        for (int i = t; i < NBUCK; i += 256) h[i] = 0;
        __syncthreads();
        const int hop = bid / NCHUNK;
        const int e0 = (bid % NCHUNK) * CHUNK;
        const int n = min(CHUNK, NEDGES - e0);
        const size_t base = (size_t)hop * NEDGES + e0;
        for (int i = t; i < n; i += 256) {
            atomicAdd(&h[rows[base + i] >> 6], 1);
        }
        __syncthreads();
        for (int i = t; i < NBUCK; i += 256) {
            if (h[i]) atomicAdd(&bucket_cnt[hop * NBUCK + i], h[i]);
        }
    } else if (bid < PREP_CASTW_END) {
        // ---- castw: W [hop][k][c] f32 -> Wt [k>>5][hop*64+c][k&31] bf16 ----
        const int idx = (bid - PREP_BHIST) * 256 + t;      // 65536 exact
        const int hop = idx >> 14;
        const int k = (idx >> 6) & 255;
        const int c = idx & 63;
        Wt[(size_t)(k >> 5) * (256 * 32) + (hop * 64 + c) * 32 + (k & 31)] = f2bf(W[idx]);
    } else {
        // ---- castx: x f32 -> Xbf bf16, 8 elems/thread (exact coverage) ----
        const size_t base = ((size_t)(bid - PREP_CASTW_END) * 256 + t) * 8;
        const float4 a = *(const float4*)&x[base];
        const float4 c = *(const float4*)&x[base + 4];
        unsigned short o[8] = {f2bf(a.x), f2bf(a.y), f2bf(a.z), f2bf(a.w),
                               f2bf(c.x), f2bf(c.y), f2bf(c.z), f2bf(c.w)};
        *(bf16x8*)&Xbf[base] = *(const bf16x8*)o;
    }
}

// ---------------------------------------------------------------------------
// K2: fused gemm (blocks 1..782) || bscan (block 0).
// A from precast Xbf (bf16x8 load + ds_write_b128, round-6 proven);
// B from the ks-contiguous Wt tile (coalesced, round-6 proven).
// ---------------------------------------------------------------------------
#define SCAN_V ((NBK_ALL + 255) / 256)   // 13
__global__ __launch_bounds__(256) void gemm_scan_kernel(const unsigned short* __restrict__ Xbf,
                                                        const unsigned short* __restrict__ Wt,
                                                        const float* __restrict__ b,
                                                        __hip_bfloat16* __restrict__ H,
                                                        const int* __restrict__ cnt,
                                                        int* __restrict__ start,
                                                        int* __restrict__ cursor) {
    __shared__ char smem[GM * LDP * 2 + 256 * LDP * 2];   // 25600 B
    const int t = threadIdx.x;

    if (blockIdx.x == 0) {
        // ---- bscan: exclusive scan of 3128 bucket counts ----
        int* s = (int*)smem;
        int v[SCAN_V];
        int tsum = 0;
#pragma unroll
        for (int i = 0; i < SCAN_V; ++i) {
            const int idx = t * SCAN_V + i;
            v[i] = (idx < NBK_ALL) ? cnt[idx] : 0;
            tsum += v[i];
        }
        s[t] = tsum;
        __syncthreads();
        for (int off = 1; off < 256; off <<= 1) {
            const int a = (t >= off) ? s[t - off] : 0;
            __syncthreads();
            s[t] += a;
            __syncthreads();
        }
        int run = s[t] - tsum;
#pragma unroll
        for (int i = 0; i < SCAN_V; ++i) {
            const int idx = t * SCAN_V + i;
            if (idx < NBK_ALL) {
                start[idx] = run;
                cursor[idx] = run;
                run += v[i];
            }
        }
        if (t == 255) start[NBK_ALL] = run;
        return;
    }

    // ---- gemm: H[n][c] = bf16( sum_k Xbf[n][k]*W[k][c] + b[c] ) ----
    unsigned short* A_lds = (unsigned short*)smem;                  // GM*LDP
    unsigned short* B_lds = (unsigned short*)(smem + GM * LDP * 2); // 256*LDP

    const int lane = t & 63;
    const int w = t >> 6;
    const int quad = lane >> 4;
    const int m16 = lane & 15;
    const int row0 = (blockIdx.x - 1) * GM;

    f32x4 acc[4][4];
#pragma unroll
    for (int mt = 0; mt < 4; ++mt)
#pragma unroll
        for (int nt = 0; nt < 4; ++nt) acc[mt][nt] = (f32x4){0.f, 0.f, 0.f, 0.f};

    for (int ks = 0; ks < 8; ++ks) {
        const int k0 = ks * 32;
        // A: thread t stages 8 bf16: row r = t>>2, k-octet (t&3)*8 (coalesced)
        {
            const int r = t >> 2;
            const int kq = (t & 3) * 8;
            bf16x8 v = {0, 0, 0, 0, 0, 0, 0, 0};
            if (row0 + r < N_NODES)
                v = *(const bf16x8*)&Xbf[(size_t)(row0 + r) * NFEAT + k0 + kq];
            *(bf16x8*)&A_lds[r * LDP + kq] = v;
        }
        // B: contiguous 16 KB ks-tile, 4 x 16 B per thread, fully coalesced
#pragma unroll
        for (int it = 0; it < 4; ++it) {
            const int i = t + it * 256;
            const bf16x8 v = *(const bf16x8*)&Wt[(size_t)ks * (256 * 32) + (size_t)i * 8];
            *(bf16x8*)&B_lds[(i >> 2) * LDP + (i & 3) * 8] = v;
        }
        __syncthreads();

        bf16x8 af[4], bf[4];
#pragma unroll
        for (int mt = 0; mt < 4; ++mt)
            af[mt] = *(const bf16x8*)&A_lds[(mt * 16 + m16) * LDP + quad * 8];
#pragma unroll
        for (int nt = 0; nt < 4; ++nt)
            bf[nt] = *(const bf16x8*)&B_lds[(w * 64 + nt * 16 + m16) * LDP + quad * 8];
#pragma unroll
        for (int mt = 0; mt < 4; ++mt)
#pragma unroll
            for (int nt = 0; nt < 4; ++nt)
                acc[mt][nt] = __builtin_amdgcn_mfma_f32_16x16x32_bf16(
                    af[mt], bf[nt], acc[mt][nt], 0, 0, 0);
        __syncthreads();
    }

#pragma unroll
    for (int nt = 0; nt < 4; ++nt) {
        const int col = w * 64 + nt * 16 + m16;
        const float bias = b[col];
#pragma unroll
        for (int mt = 0; mt < 4; ++mt) {
#pragma unroll
            for (int r = 0; r < 4; ++r) {
                const int row = row0 + mt * 16 + quad * 4 + r;
                if (row < N_NODES)
                    H[(size_t)row * 256 + col] = __float2bfloat16(acc[mt][nt][r] + bias);
            }
        }
    }
}

// ---------------------------------------------------------------------------
// Legacy f32-input GEMM (fallback path only).
// ---------------------------------------------------------------------------
__global__ __launch_bounds__(256) void gemm_mfma_kernel(const float* __restrict__ x,
                                                        const float* __restrict__ W,
                                                        const float* __restrict__ b,
                                                        __hip_bfloat16* __restrict__ H) {
    __shared__ unsigned short A_lds[GM * LDP];
    __shared__ unsigned short B_lds[256 * LDP];

    const int t = threadIdx.x;
    const int lane = t & 63;
    const int w = t >> 6;
    const int quad = lane >> 4;
    const int m16 = lane & 15;
    const int row0 = blockIdx.x * GM;

    f32x4 acc[4][4];
#pragma unroll
    for (int mt = 0; mt < 4; ++mt)
#pragma unroll
        for (int nt = 0; nt < 4; ++nt) acc[mt][nt] = (f32x4){0.f, 0.f, 0.f, 0.f};

    for (int ks = 0; ks < 8; ++ks) {
        const int k0 = ks * 32;
#pragma unroll
        for (int it = 0; it < 2; ++it) {
            const int i = t + it * 256;
            const int r = i >> 3;
            const int kq = (i & 7) * 4;
            float4 v = make_float4(0.f, 0.f, 0.f, 0.f);
            if (row0 + r < N_NODES)
                v = *(const float4*)&x[(size_t)(row0 + r) * NFEAT + k0 + kq];
            unsigned short* d = &A_lds[r * LDP + kq];
            d[0] = f2bf(v.x); d[1] = f2bf(v.y); d[2] = f2bf(v.z); d[3] = f2bf(v.w);
        }
#pragma unroll
        for (int it = 0; it < 8; ++it) {
            const int i = t + it * 256;
            const int n4 = i & 63;
            const int kk = i >> 6;
            const int hop = n4 >> 4;
            const int j = (n4 & 15) * 4;
            const float4 v = *(const float4*)&W[(size_t)hop * (NFEAT * NHID)
                                                + (size_t)(k0 + kk) * NHID + j];
            B_lds[(n4 * 4 + 0) * LDP + kk] = f2bf(v.x);
            B_lds[(n4 * 4 + 1) * LDP + kk] = f2bf(v.y);
            B_lds[(n4 * 4 + 2) * LDP + kk] = f2bf(v.z);
            B_lds[(n4 * 4 + 3) * LDP + kk] = f2bf(v.w);
        }
        __syncthreads();

        bf16x8 af[4], bf[4];
#pragma unroll
        for (int mt = 0; mt < 4; ++mt)
            af[mt] = *(const bf16x8*)&A_lds[(mt * 16 + m16) * LDP + quad * 8];
#pragma unroll
        for (int nt = 0; nt < 4; ++nt)
            bf[nt] = *(const bf16x8*)&B_lds[(w * 64 + nt * 16 + m16) * LDP + quad * 8];
#pragma unroll
        for (int mt = 0; mt < 4; ++mt)
#pragma unroll
            for (int nt = 0; nt < 4; ++nt)
                acc[mt][nt] = __builtin_amdgcn_mfma_f32_16x16x32_bf16(
                    af[mt], bf[nt], acc[mt][nt], 0, 0, 0);
        __syncthreads();
    }

#pragma unroll
    for (int nt = 0; nt < 4; ++nt) {
        const int col = w * 64 + nt * 16 + m16;
        const float bias = b[col];
#pragma unroll
        for (int mt = 0; mt < 4; ++mt) {
#pragma unroll
            for (int r = 0; r < 4; ++r) {
                const int row = row0 + mt * 16 + quad * 4 + r;
                if (row < N_NODES)
                    H[(size_t)row * 256 + col] = __float2bfloat16(acc[mt][nt][r] + bias);
            }
        }
    }
}

// ---------------------------------------------------------------------------
// K3: coarse partition into 64-row buckets via LDS counting sort (round-6
// exact, 71.5 us known). Payload: {(row<<16)|col, float_bits(val)}.
// grid = (NCHUNK, HOPS)
// ---------------------------------------------------------------------------
__global__ __launch_bounds__(256) void partition_kernel(const int* __restrict__ rows,
                                                        const int* __restrict__ cols,
                                                        const float* __restrict__ vals,
                                                        int* __restrict__ cursor,
                                                        int2* __restrict__ partbuf) {
    __shared__ int2 pay[CHUNK];                     // 32 KB
    __shared__ int h[NBUCK], excl[NBUCK], gbase[NBUCK], lcur[NBUCK];  // 12.5 KB
    __shared__ int s[256];
    const int t = threadIdx.x;
    const int hop = blockIdx.y;
    const int e0 = blockIdx.x * CHUNK;
    const int n = min(CHUNK, NEDGES - e0);
    const size_t base = (size_t)hop * NEDGES + e0;

    for (int i = t; i < NBUCK; i += 256) h[i] = 0;
    __syncthreads();

    int myrow[CHUNK / 256];
#pragma unroll
    for (int j = 0; j < CHUNK / 256; ++j) {
        const int i = t + j * 256;
        if (i < n) {
            const int r = rows[base + i];
            myrow[j] = r;
            atomicAdd(&h[r >> 6], 1);
        }
    }
    __syncthreads();

    int pv[4];
    int tsum = 0;
#pragma unroll
    for (int i = 0; i < 4; ++i) {
        const int idx = t * 4 + i;
        pv[i] = (idx < NBUCK) ? h[idx] : 0;
        tsum += pv[i];
    }
    s[t] = tsum;
    __syncthreads();
    for (int off = 1; off < 256; off <<= 1) {
        const int a = (t >= off) ? s[t - off] : 0;
        __syncthreads();
        s[t] += a;
        __syncthreads();
    }
    int run = s[t] - tsum;
#pragma unroll
    for (int i = 0; i < 4; ++i) {
        const int idx = t * 4 + i;
        if (idx < NBUCK) {
            excl[idx] = run;
            lcur[idx] = run;
            gbase[idx] = pv[i] ? atomicAdd(&cursor[hop * NBUCK + idx], pv[i]) : 0;
            run += pv[i];
        }
    }
    __syncthreads();

#pragma unroll
    for (int j = 0; j < CHUNK / 256; ++j) {
        const int i = t + j * 256;
        if (i < n) {
            const int r = myrow[j];
            const int c = cols[base + i];
            const float v = vals[base + i];
            const int pos = atomicAdd(&lcur[r >> 6], 1);
            pay[pos] = make_int2((r << 16) | c, __float_as_int(v));
        }
    }
    __syncthreads();

    for (int i = t; i < n; i += 256) {
        const int2 p = pay[i];
        const int bk = ((unsigned)p.x) >> 22;       // row >> 6
        partbuf[gbase[bk] + (i - excl[bk])] = p;
    }
}

// ---------------------------------------------------------------------------
// K4: sortgather (round-8 exact, 82 us known). Block = one (bucket, hop):
// stage bucket edges to registers + LDS row-histogram (int atomics) -> scan
// -> counting-scatter into sorted LDS M with rowptr -> dual-group inner loop.
// grid = (NBUCK, HOPS)
// ---------------------------------------------------------------------------
__global__ __launch_bounds__(256) void sortgather_kernel(const __hip_bfloat16* __restrict__ H,
                                                         const int* __restrict__ start,
                                                         const int2* __restrict__ partbuf,
                                                         float* __restrict__ out) {
    __shared__ int2 M[CAP + 16];                    // 16.5 KB sorted {col,val}
    __shared__ int rowptr[BROWS + 1];
    __shared__ int h[BROWS], cur[BROWS];
    __shared__ int s[256];
    const int t = threadIdx.x;
    const int f = t & 63;
    const int w = t >> 6;
    const int gi = f >> 5;                          // edge sub-group 0/1
    const int fp = f & 31;                          // feature-pair index
    const int hop = blockIdx.y;
    const int bucket = blockIdx.x;
    const int g = hop * NBUCK + bucket;
    const int s0 = start[g];
    const int cnt = start[g + 1] - s0;
    const int row0w = bucket * BROWS + w * 16;

    const char* Hb = (const char*)H + hop * 128 + fp * 4;

    float aL[16], aH[16];
#pragma unroll
    for (int r = 0; r < 16; ++r) { aL[r] = 0.f; aH[r] = 0.f; }

    for (int base = 0; base < cnt; base += CAP) {
        const int n = min(CAP, cnt - base);
        if (t < BROWS) h[t] = 0;
        __syncthreads();

        // pass A: coalesced load to registers + row histogram (int LDS atomics)
        int2 myp[CAP / 256];
#pragma unroll
        for (int k = 0; k < CAP / 256; ++k) {
            const int i = t + k * 256;
            if (i < n) {
                const int2 p = partbuf[s0 + base + i];
                myp[k] = p;
                atomicAdd(&h[((unsigned)p.x >> 16) & (BROWS - 1)], 1);
            }
        }
        __syncthreads();

        // scan h[64] -> rowptr (exclusive), cur
        const int hv = (t < BROWS) ? h[t] : 0;
        s[t] = hv;
        __syncthreads();
        for (int off = 1; off < BROWS; off <<= 1) {
            const int a = (t >= off) ? s[t - off] : 0;
            __syncthreads();
            s[t] += a;
            __syncthreads();
        }
        if (t < BROWS) {
            rowptr[t] = s[t] - hv;
            cur[t] = s[t] - hv;
        }
        if (t == 0) rowptr[BROWS] = n;
        __syncthreads();

        // pass B: counting-scatter into sorted M ({col, val})
#pragma unroll
        for (int k = 0; k < CAP / 256; ++k) {
            const int i = t + k * 256;
            if (i < n) {
                const int2 p = myp[k];
                const int rl = ((unsigned)p.x >> 16) & (BROWS - 1);
                const int pos = atomicAdd(&cur[rl], 1);
                M[pos] = make_int2(p.x & 0xFFFF, p.y);
            }
        }
        if (t < 16) M[n + t] = make_int2(0, 0);     // pad for tail predication
        __syncthreads();

        // compute: wave w owns rows w*16..w*16+15
        int off_l = 0;
        if (f <= 16) off_l = rowptr[w * 16 + f];
#pragma unroll
        for (int r = 0; r < 16; ++r) {
            const int sE = __builtin_amdgcn_readlane(off_l, r);
            const int e2 = __builtin_amdgcn_readlane(off_l, r + 1);
            for (int gg = sE; gg < e2; gg += 16) {
                int2 mm[8];
#pragma unroll
                for (int j = 0; j < 8; ++j) mm[j] = M[gg + gi * 8 + j];
                unsigned hv8[8];
#pragma unroll
                for (int j = 0; j < 8; ++j)
                    hv8[j] = *(const unsigned*)(Hb + ((size_t)(unsigned)mm[j].x << 9));
#pragma unroll
                for (int j = 0; j < 8; ++j) {
                    const float vj = (gg + gi * 8 + j < e2) ? __int_as_float(mm[j].y) : 0.f;
                    aL[r] = fmaf(vj, __uint_as_float(hv8[j] << 16), aL[r]);
                    aH[r] = fmaf(vj, __uint_as_float(hv8[j] & 0xffff0000u), aH[r]);
                }
            }
        }
        __syncthreads();                            // M stable until next tile's pass B
    }

    // epilogue: fold halves, ELU, store float2 from lanes 0-31
    float* outp = out + (size_t)row0w * 256 + hop * 64 + fp * 2;
#pragma unroll
    for (int r = 0; r < 16; ++r) {
        float lo = aL[r] + __shfl_xor(aL[r], 32, 64);
        float hi = aH[r] + __shfl_xor(aH[r], 32, 64);
        lo = lo > 0.f ? lo : __expf(lo) - 1.f;
        hi = hi > 0.f ? hi : __expf(hi) - 1.f;
        if (f < 32 && row0w + r < N_NODES)
            *(float2*)(outp + (size_t)r * 256) = make_float2(lo, hi);
    }
}

// ---------------------------------------------------------------------------
// Fallback path (atomic scatter) if workspace is too small.
// ---------------------------------------------------------------------------
#define EPW 8
__global__ __launch_bounds__(256) void scatter_kernel(const __hip_bfloat16* __restrict__ H,
                                                      const int* __restrict__ rows,
                                                      const int* __restrict__ cols,
                                                      const float* __restrict__ vals,
                                                      float* __restrict__ out) {
    const int lane = threadIdx.x & 63;
    const int wid = __builtin_amdgcn_readfirstlane(threadIdx.x >> 6);
    const int hop = blockIdx.y;
    const int e0 = (blockIdx.x * 4 + wid) * EPW;
    const int base = hop * NEDGES;
    const int hoff = hop * 64 + lane;
#pragma unroll
    for (int i = 0; i < EPW; ++i) {
        const int e = e0 + i;
        const int r = rows[base + e];
        const int c = cols[base + e];
        const float v = vals[base + e];
        unsafeAtomicAdd(&out[(size_t)r * 256 + hoff],
                        v * __bfloat162float(H[(size_t)c * 256 + hoff]));
    }
}

__global__ __launch_bounds__(256) void elu_kernel(float* __restrict__ out, int n4) {
    const int i = blockIdx.x * 256 + threadIdx.x;
    if (i < n4) {
        float4 v = ((float4*)out)[i];
        v.x = v.x > 0.f ? v.x : expf(v.x) - 1.f;
        v.y = v.y > 0.f ? v.y : expf(v.y) - 1.f;
        v.z = v.z > 0.f ? v.z : expf(v.z) - 1.f;
        v.w = v.w > 0.f ? v.w : expf(v.w) - 1.f;
        ((float4*)out)[i] = v;
    }
}

extern "C" void kernel_launch(void* const* d_in, const int* in_sizes, int n_in,
                              void* d_out, int out_size, void* d_ws, size_t ws_size,
                              hipStream_t stream) {
    const float* x        = (const float*)d_in[0];
    const float* W        = (const float*)d_in[1];
    const float* b        = (const float*)d_in[2];
    const int*   adj_rows = (const int*)d_in[3];
    const int*   adj_cols = (const int*)d_in[4];
    const float* adj_vals = (const float*)d_in[5];
    float* out = (float*)d_out;

    // Workspace layout (~51.4 MB)
    char* w = (char*)d_ws;
    size_t off = 0;
    __hip_bfloat16* H = (__hip_bfloat16*)(w + off);
    off += (size_t)N_NODES * 256 * 2;                                          // 25.6 MB
    int2*  partbuf    = (int2*)(w + off);  off += (size_t)HOPS * NEDGES * 8;   // 25.6 MB
    int*   bucket_cnt = (int*)(w + off);   off += ((size_t)NBK_ALL * 4 + 255) & ~255ull;
    int*   bstart     = (int*)(w + off);   off += (((size_t)NBK_ALL + 1) * 4 + 255) & ~255ull;
    int*   bcursor    = (int*)(w + off);   off += ((size_t)NBK_ALL * 4 + 255) & ~255ull;
    unsigned short* Wt = (unsigned short*)(w + off);
    off += (size_t)HOPS * NFEAT * NHID * 2;                                    // 128 KB
    const bool use_sorted = (ws_size >= off);

    // Alias: Xbf lives in the partbuf region (dead until partition_kernel,
    // which runs strictly after gemm_scan in-stream).
    unsigned short* Xbf = (unsigned short*)partbuf;

    if (use_sorted) {
        hipMemsetAsync(bucket_cnt, 0, (size_t)NBK_ALL * 4, stream);
        // K1: bhist || castw || castx
        prep_kernel<<<PREP_TOTAL, 256, 0, stream>>>(x, Xbf, W, Wt, adj_rows, bucket_cnt);
        // K2: bscan (block 0) || gemm (blocks 1..782), A from precast Xbf
        gemm_scan_kernel<<<NGBLK + 1, 256, 0, stream>>>(Xbf, Wt, b, H,
                                                        bucket_cnt, bstart, bcursor);
        // K3: coarse partition
        partition_kernel<<<dim3(NCHUNK, HOPS), 256, 0, stream>>>(adj_rows, adj_cols,
                                                                 adj_vals, bcursor, partbuf);
        // K4: fused sort + gather
        sortgather_kernel<<<dim3(NBUCK, HOPS), 256, 0, stream>>>(H, bstart, partbuf, out);
    } else {
        gemm_mfma_kernel<<<NGBLK, 256, 0, stream>>>(x, W, b, H);
        hipMemsetAsync(d_out, 0, (size_t)out_size * sizeof(float), stream);
        scatter_kernel<<<dim3(NEDGES / (4 * EPW), HOPS), 256, 0, stream>>>(
            H, adj_rows, adj_cols, adj_vals, out);
        elu_kernel<<<(out_size / 4 + 255) / 256, 256, 0, stream>>>(out, out_size / 4);
    }
}